// Round 7
// baseline (164.331 us; speedup 1.0000x reference)
//
#include <hip/hip_runtime.h>
#include <hip/hip_bf16.h>

// Problem constants (from reference): B=2, C=3, H=W=64, N=4096.
namespace {
constexpr int BB = 2;
constexpr int NN = 4096;

// Workspace layout. Small fp32 arrays first (element offsets in floats):
constexpr int OFF_SRC4 = 0;             // float4[B*N]
constexpr int OFF_TAR4 = 4 * BB * NN;   // float4[B*N]
constexpr int OFF_U4   = 8 * BB * NN;   // float4[B*N] (ux,uy,uz,|u|^2)
constexpr int OFF_W4   = 12 * BB * NN;  // float4[B*N] normalized diff dir
constexpr int OFF_ROW  = 16 * BB * NN;  // float2[B*N] (m2_i log2-domain row max, 1/den_i)
constexpr int OFF_CS   = 18 * BB * NN;  // float[B*N]  column S accumulators (zeroed)
constexpr int OFF_NMAX = 19 * BB * NN;  // float[B]    max|src| (zeroed, right after CS)
// fp16 N x N stream (byte offset): E_ij column-softmax numerators
constexpr size_t OFF_EB = (size_t)1 << 20;
constexpr float L2E = 1.4426950408889634f;   // log2(e)
constexpr float S50 = 72.13475204444817f;    // 50 * log2(e)
constexpr float BIAS = 10.0f;                // fp16 underflow headroom for E
}

__device__ __forceinline__ float fsqrt(float x) { return __builtin_amdgcn_sqrtf(x); }
__device__ __forceinline__ float ex2(float x) { return __builtin_amdgcn_exp2f(x); }
__device__ __forceinline__ float frcp(float x) { return __builtin_amdgcn_rcpf(x); }

// ---------------------------------------------------------------------------
// Setup: per-batch M = K R K^-1, o = K t; per-pixel fp32 arrays; max|src| per b.
// ---------------------------------------------------------------------------
__global__ __launch_bounds__(256) void k_setup(
    const float* __restrict__ fsrc, const float* __restrict__ ftar,
    const float* __restrict__ Kb, const float* __restrict__ Rb,
    const float* __restrict__ tb, float* __restrict__ ws) {
  int gid = blockIdx.x * blockDim.x + threadIdx.x;
  if (gid >= BB * NN) return;
  int b = gid >> 12;
  int n = gid & (NN - 1);

  float K[9], R[9], t3[3];
#pragma unroll
  for (int k = 0; k < 9; k++) { K[k] = Kb[b * 9 + k]; R[k] = Rb[b * 9 + k]; }
#pragma unroll
  for (int k = 0; k < 3; k++) t3[k] = tb[b * 3 + k];

  float c00 = K[4] * K[8] - K[5] * K[7];
  float c01 = K[5] * K[6] - K[3] * K[8];
  float c02 = K[3] * K[7] - K[4] * K[6];
  float det = K[0] * c00 + K[1] * c01 + K[2] * c02;
  float id = 1.0f / det;
  float Ki[9];
  Ki[0] = c00 * id; Ki[1] = (K[2] * K[7] - K[1] * K[8]) * id; Ki[2] = (K[1] * K[5] - K[2] * K[4]) * id;
  Ki[3] = c01 * id; Ki[4] = (K[0] * K[8] - K[2] * K[6]) * id; Ki[5] = (K[2] * K[3] - K[0] * K[5]) * id;
  Ki[6] = c02 * id; Ki[7] = (K[1] * K[6] - K[0] * K[7]) * id; Ki[8] = (K[0] * K[4] - K[1] * K[3]) * id;

  float RK[9];
#pragma unroll
  for (int i = 0; i < 3; i++)
#pragma unroll
    for (int j = 0; j < 3; j++)
      RK[i * 3 + j] = R[i * 3 + 0] * Ki[j] + R[i * 3 + 1] * Ki[3 + j] + R[i * 3 + 2] * Ki[6 + j];
  float M3[9];
#pragma unroll
  for (int i = 0; i < 3; i++)
#pragma unroll
    for (int j = 0; j < 3; j++)
      M3[i * 3 + j] = K[i * 3 + 0] * RK[j] + K[i * 3 + 1] * RK[3 + j] + K[i * 3 + 2] * RK[6 + j];
  float o0 = K[0] * t3[0] + K[1] * t3[1] + K[2] * t3[2];
  float o1 = K[3] * t3[0] + K[4] * t3[1] + K[5] * t3[2];
  float o2 = K[6] * t3[0] + K[7] * t3[1] + K[8] * t3[2];

  float sx = fsrc[b * 3 * NN + 0 * NN + n];
  float sy = fsrc[b * 3 * NN + 1 * NN + n];
  float sz = fsrc[b * 3 * NN + 2 * NN + n];
  float tx = ftar[b * 3 * NN + 0 * NN + n];
  float ty = ftar[b * 3 * NN + 1 * NN + n];
  float tz = ftar[b * 3 * NN + 2 * NN + n];

  float ux = sx - o0, uy = sy - o1, uz = sz - o2;
  float usq = ux * ux + uy * uy + uz * uz;

  float px = (float)(n >> 6), py = (float)(n & 63);
  float vx = M3[0] * px + M3[1] * py + M3[2];
  float vy = M3[3] * px + M3[4] * py + M3[5];
  float vz = M3[6] * px + M3[7] * py + M3[8];
  float invn = rsqrtf(vx * vx + vy * vy + vz * vz);

  float4* src4 = (float4*)(ws + OFF_SRC4);
  float4* tar4 = (float4*)(ws + OFF_TAR4);
  float4* u4 = (float4*)(ws + OFF_U4);
  float4* w4 = (float4*)(ws + OFF_W4);
  src4[gid] = make_float4(sx, sy, sz, 0.f);
  tar4[gid] = make_float4(tx, ty, tz, 0.f);
  u4[gid] = make_float4(ux, uy, uz, usq);
  w4[gid] = make_float4(vx * invn, vy * invn, vz * invn, 0.f);

  float ns = fsqrt(sx * sx + sy * sy + sz * sz);
#pragma unroll
  for (int off = 32; off; off >>= 1) ns = fmaxf(ns, __shfl_xor(ns, off));
  if ((threadIdx.x & 63) == 0)
    atomicMax((unsigned int*)(ws + OFF_NMAX + b), __float_as_uint(ns));
}

// ---------------------------------------------------------------------------
// Pass 1: row softmax stats over j (exp2 domain). Block = 4 waves on 8 rows,
// j split 4 ways. Loop A: true max d2 (cheap, no trans). Loop B: den sum.
// Writes float2 (m2_i, 1/den_i). No N^2 store.
// ---------------------------------------------------------------------------
__global__ __launch_bounds__(256, 4) void k_pass1(float* __restrict__ ws) {
  __shared__ float sred[4][8];
  const float4* u4 = (const float4*)(ws + OFF_U4);
  const float4* w4 = (const float4*)(ws + OFF_W4);
  float2* rowst = (float2*)(ws + OFF_ROW);
  int tid = threadIdx.x, wid = tid >> 6, lane = tid & 63;
  int g0 = blockIdx.x * 8;
  int b = g0 >> 12;

  float ux[8], uy[8], uz[8], us[8];
#pragma unroll
  for (int r = 0; r < 8; r++) {
    float4 u = u4[g0 + r];
    ux[r] = u.x; uy[r] = u.y; uz[r] = u.z; us[r] = u.w;
  }
  const float4* wb = w4 + b * NN;

  // Loop A: max d2
  float mx[8] = {0.f, 0.f, 0.f, 0.f, 0.f, 0.f, 0.f, 0.f};
  for (int j = wid * 64 + lane; j < NN; j += 256) {
    float4 w = wb[j];
#pragma unroll
    for (int r = 0; r < 8; r++) {
      float dot = ux[r] * w.x + uy[r] * w.y + uz[r] * w.z;
      mx[r] = fmaxf(mx[r], us[r] - dot * dot);
    }
  }
#pragma unroll
  for (int off = 32; off; off >>= 1)
#pragma unroll
    for (int r = 0; r < 8; r++) mx[r] = fmaxf(mx[r], __shfl_xor(mx[r], off));
  if (lane == 0) {
#pragma unroll
    for (int r = 0; r < 8; r++) sred[wid][r] = mx[r];
  }
  __syncthreads();
  float m2[8];
#pragma unroll
  for (int r = 0; r < 8; r++)
    m2[r] = S50 * fsqrt(fmaxf(fmaxf(sred[0][r], sred[1][r]), fmaxf(sred[2][r], sred[3][r])));
  __syncthreads();

  // Loop B: den sum
  float s[8] = {0.f, 0.f, 0.f, 0.f, 0.f, 0.f, 0.f, 0.f};
  for (int j = wid * 64 + lane; j < NN; j += 256) {
    float4 w = wb[j];
#pragma unroll
    for (int r = 0; r < 8; r++) {
      float dot = ux[r] * w.x + uy[r] * w.y + uz[r] * w.z;
      float d2 = fmaxf(us[r] - dot * dot, 0.f);
      float t = fsqrt(d2);
      s[r] += ex2(fmaf(S50, t, -m2[r]));
    }
  }
#pragma unroll
  for (int off = 32; off; off >>= 1)
#pragma unroll
    for (int r = 0; r < 8; r++) s[r] += __shfl_xor(s[r], off);
  if (lane == 0) {
#pragma unroll
    for (int r = 0; r < 8; r++) sred[wid][r] = s[r];
  }
  __syncthreads();
  if (tid < 8) {
    float tot = sred[0][tid] + sred[1][tid] + sred[2][tid] + sred[3][tid];
    rowst[g0 + tid] = make_float2(m2[tid], 1.f / tot);
  }
}

// ---------------------------------------------------------------------------
// Pass 2: column softmax numerators + denominators, recomputing e on the fly.
// Lane <-> column: wave owns 64 consecutive columns (w_j, tar_j consts in
// VGPRs); loops i with wave-uniform scalar loads (u_i, src_i, m2_i, invden_i).
// E_ij = exp2(A'*wgt + BIAS - Mb2_j) stored fp16; S_j via LDS + one atomicAdd
// per column per block. Grid: 128 col-groups x 16 i-chunks = 2048 blocks.
// ---------------------------------------------------------------------------
__global__ __launch_bounds__(256, 8) void k_pass2(float* __restrict__ ws) {
  __shared__ float sS[4][64];
  const float4* u4 = (const float4*)(ws + OFF_U4);
  const float4* w4 = (const float4*)(ws + OFF_W4);
  const float4* src4 = (const float4*)(ws + OFF_SRC4);
  const float4* tar4 = (const float4*)(ws + OFF_TAR4);
  const float2* rowst = (const float2*)(ws + OFF_ROW);
  float* CS = ws + OFF_CS;
  _Float16* Eh = (_Float16*)((char*)ws + OFF_EB);

  int tid = threadIdx.x, wid = tid >> 6, lane = tid & 63;
  int g = blockIdx.x >> 4;        // col-group 0..127
  int c = blockIdx.x & 15;        // i-chunk 0..15
  int gc = g * 64 + lane;         // global column index (b*N + j_local)
  int b = gc >> 12;
  int base = b * NN;
  int jloc = gc - base;
  float maxns = ws[OFF_NMAX + b];

  float4 wj = w4[gc];
  float4 tt = tar4[gc];
  float Cj = BIAS - maxns * L2E * fsqrt(tt.x * tt.x + tt.y * tt.y + tt.z * tt.z);
  float txl = tt.x * L2E, tyl = tt.y * L2E, tzl = tt.z * L2E;

  float S = 0.f;
  int i0 = c * 256 + wid * 64;
#pragma unroll 4
  for (int it = 0; it < 64; ++it) {
    int i = i0 + it;                       // wave-uniform local row
    float4 uv = u4[base + i];              // uniform (scalar load)
    float4 sv = src4[base + i];            // uniform
    float2 rs = rowst[base + i];           // uniform (m2, invden)
    float dot = uv.x * wj.x + uv.y * wj.y + uv.z * wj.z;
    float d2 = fmaxf(uv.w - dot * dot, 0.f);
    float t = fsqrt(d2);
    float ev = ex2(fmaf(S50, t, -rs.x));
    float wgt = fmaf(-ev, rs.y, 1.f);
    float Ap = sv.x * txl + sv.y * tyl + sv.z * tzl;
    float Ev = ex2(fmaf(Ap, wgt, Cj));
    S += Ev;
    Eh[(size_t)(base + i) * NN + jloc] = (_Float16)Ev;
  }
  sS[wid][lane] = S;
  __syncthreads();
  if (wid == 0) {
    float tot = sS[0][lane] + sS[1][lane] + sS[2][lane] + sS[3][lane];
    atomicAdd(&CS[gc], tot);
  }
}

// ---------------------------------------------------------------------------
// Pass 3: out[i,c] = sum_j (E_ij / S_j) * src_j. Block = 4 waves on 4 rows,
// j split 4 ways. No transcendentals; pure fp16-load + FMA stream.
// ---------------------------------------------------------------------------
__global__ __launch_bounds__(256, 8) void k_pass3(const float* __restrict__ ws,
                                                  float* __restrict__ out) {
  __shared__ float sacc[4][12];
  const float4* src4 = (const float4*)(ws + OFF_SRC4);
  const float* CS = ws + OFF_CS;
  const _Float16* Eh = (const _Float16*)((const char*)ws + OFF_EB);
  int tid = threadIdx.x, wid = tid >> 6, lane = tid & 63;
  int g0 = blockIdx.x * 4;
  int b = g0 >> 12;
  int base = b * NN;

  float acc[4][3];
#pragma unroll
  for (int r = 0; r < 4; r++) { acc[r][0] = 0.f; acc[r][1] = 0.f; acc[r][2] = 0.f; }

#pragma unroll 2
  for (int j = wid * 64 + lane; j < NN; j += 256) {
    float4 sj = src4[base + j];
    float invS = frcp(CS[base + j]);
#pragma unroll
    for (int r = 0; r < 4; r++) {
      float Ev = (float)Eh[(size_t)(g0 + r) * NN + j];
      float p = Ev * invS;
      acc[r][0] += p * sj.x;
      acc[r][1] += p * sj.y;
      acc[r][2] += p * sj.z;
    }
  }
#pragma unroll
  for (int off = 32; off; off >>= 1)
#pragma unroll
    for (int r = 0; r < 4; r++) {
      acc[r][0] += __shfl_xor(acc[r][0], off);
      acc[r][1] += __shfl_xor(acc[r][1], off);
      acc[r][2] += __shfl_xor(acc[r][2], off);
    }
  if (lane == 0) {
#pragma unroll
    for (int r = 0; r < 4; r++) {
      sacc[wid][r * 3 + 0] = acc[r][0];
      sacc[wid][r * 3 + 1] = acc[r][1];
      sacc[wid][r * 3 + 2] = acc[r][2];
    }
  }
  __syncthreads();
  if (tid < 12) {
    float v = sacc[0][tid] + sacc[1][tid] + sacc[2][tid] + sacc[3][tid];
    out[g0 * 3 + tid] = v;
  }
}

extern "C" void kernel_launch(void* const* d_in, const int* in_sizes, int n_in,
                              void* d_out, int out_size, void* d_ws, size_t ws_size,
                              hipStream_t stream) {
  (void)in_sizes; (void)n_in; (void)out_size; (void)ws_size;
  const float* ftar = (const float*)d_in[0];
  const float* fsrc = (const float*)d_in[1];
  const float* K = (const float*)d_in[2];
  const float* R = (const float*)d_in[3];
  const float* t = (const float*)d_in[4];
  float* ws = (float*)d_ws;
  float* out = (float*)d_out;

  // zero the column-S accumulators + per-batch norm-max (contiguous region)
  hipMemsetAsync((char*)d_ws + (size_t)OFF_CS * sizeof(float), 0,
                 (size_t)(BB * NN + BB) * sizeof(float), stream);

  k_setup<<<dim3((BB * NN + 255) / 256), dim3(256), 0, stream>>>(fsrc, ftar, K, R, t, ws);
  k_pass1<<<dim3(1024), dim3(256), 0, stream>>>(ws);
  k_pass2<<<dim3(2048), dim3(256), 0, stream>>>(ws);
  k_pass3<<<dim3(2048), dim3(256), 0, stream>>>(ws, out);
}

// Round 8
// 140.735 us; speedup vs baseline: 1.1677x; 1.1677x over previous
//
#include <hip/hip_runtime.h>
#include <hip/hip_bf16.h>

// Problem constants (from reference): B=2, C=3, H=W=64, N=4096.
namespace {
constexpr int BB = 2;
constexpr int NN = 4096;

// Workspace layout. Small fp32 arrays first (element offsets in floats):
constexpr int OFF_SRC4 = 0;             // float4[B*N]
constexpr int OFF_TAR4 = 4 * BB * NN;   // float4[B*N]
constexpr int OFF_U4   = 8 * BB * NN;   // float4[B*N] (ux,uy,uz,|u|^2)
constexpr int OFF_W4   = 12 * BB * NN;  // float4[B*N] normalized diff dir
constexpr int OFF_ROW  = 16 * BB * NN;  // float2[B*N] (m2_i log2-domain row max, 1/den_i)
constexpr int OFF_CS   = 18 * BB * NN;  // float[B*N]  1/S_j (written whole by pass2)
constexpr int OFF_NMAX = 19 * BB * NN;  // float[B]    max|src| (zeroed)
// fp16 N x N stream, COLUMN-major: E[(global_col)*NN + i_local]
constexpr size_t OFF_EB = (size_t)1 << 20;
constexpr float L2E = 1.4426950408889634f;   // log2(e)
constexpr float S50 = 72.13475204444817f;    // 50 * log2(e)
constexpr float BIAS = 10.0f;                // fp16 underflow headroom for E
}

__device__ __forceinline__ float fsqrt(float x) { return __builtin_amdgcn_sqrtf(x); }
__device__ __forceinline__ float ex2(float x) { return __builtin_amdgcn_exp2f(x); }

// ---------------------------------------------------------------------------
// Setup: per-batch M = K R K^-1, o = K t; per-pixel fp32 arrays; max|src| per b.
// ---------------------------------------------------------------------------
__global__ __launch_bounds__(256) void k_setup(
    const float* __restrict__ fsrc, const float* __restrict__ ftar,
    const float* __restrict__ Kb, const float* __restrict__ Rb,
    const float* __restrict__ tb, float* __restrict__ ws) {
  int gid = blockIdx.x * blockDim.x + threadIdx.x;
  if (gid >= BB * NN) return;
  int b = gid >> 12;
  int n = gid & (NN - 1);

  float K[9], R[9], t3[3];
#pragma unroll
  for (int k = 0; k < 9; k++) { K[k] = Kb[b * 9 + k]; R[k] = Rb[b * 9 + k]; }
#pragma unroll
  for (int k = 0; k < 3; k++) t3[k] = tb[b * 3 + k];

  float c00 = K[4] * K[8] - K[5] * K[7];
  float c01 = K[5] * K[6] - K[3] * K[8];
  float c02 = K[3] * K[7] - K[4] * K[6];
  float det = K[0] * c00 + K[1] * c01 + K[2] * c02;
  float id = 1.0f / det;
  float Ki[9];
  Ki[0] = c00 * id; Ki[1] = (K[2] * K[7] - K[1] * K[8]) * id; Ki[2] = (K[1] * K[5] - K[2] * K[4]) * id;
  Ki[3] = c01 * id; Ki[4] = (K[0] * K[8] - K[2] * K[6]) * id; Ki[5] = (K[2] * K[3] - K[0] * K[5]) * id;
  Ki[6] = c02 * id; Ki[7] = (K[1] * K[6] - K[0] * K[7]) * id; Ki[8] = (K[0] * K[4] - K[1] * K[3]) * id;

  float RK[9];
#pragma unroll
  for (int i = 0; i < 3; i++)
#pragma unroll
    for (int j = 0; j < 3; j++)
      RK[i * 3 + j] = R[i * 3 + 0] * Ki[j] + R[i * 3 + 1] * Ki[3 + j] + R[i * 3 + 2] * Ki[6 + j];
  float M3[9];
#pragma unroll
  for (int i = 0; i < 3; i++)
#pragma unroll
    for (int j = 0; j < 3; j++)
      M3[i * 3 + j] = K[i * 3 + 0] * RK[j] + K[i * 3 + 1] * RK[3 + j] + K[i * 3 + 2] * RK[6 + j];
  float o0 = K[0] * t3[0] + K[1] * t3[1] + K[2] * t3[2];
  float o1 = K[3] * t3[0] + K[4] * t3[1] + K[5] * t3[2];
  float o2 = K[6] * t3[0] + K[7] * t3[1] + K[8] * t3[2];

  float sx = fsrc[b * 3 * NN + 0 * NN + n];
  float sy = fsrc[b * 3 * NN + 1 * NN + n];
  float sz = fsrc[b * 3 * NN + 2 * NN + n];
  float tx = ftar[b * 3 * NN + 0 * NN + n];
  float ty = ftar[b * 3 * NN + 1 * NN + n];
  float tz = ftar[b * 3 * NN + 2 * NN + n];

  float ux = sx - o0, uy = sy - o1, uz = sz - o2;
  float usq = ux * ux + uy * uy + uz * uz;

  float px = (float)(n >> 6), py = (float)(n & 63);
  float vx = M3[0] * px + M3[1] * py + M3[2];
  float vy = M3[3] * px + M3[4] * py + M3[5];
  float vz = M3[6] * px + M3[7] * py + M3[8];
  float invn = rsqrtf(vx * vx + vy * vy + vz * vz);

  float4* src4 = (float4*)(ws + OFF_SRC4);
  float4* tar4 = (float4*)(ws + OFF_TAR4);
  float4* u4 = (float4*)(ws + OFF_U4);
  float4* w4 = (float4*)(ws + OFF_W4);
  src4[gid] = make_float4(sx, sy, sz, 0.f);
  tar4[gid] = make_float4(tx, ty, tz, 0.f);
  u4[gid] = make_float4(ux, uy, uz, usq);
  w4[gid] = make_float4(vx * invn, vy * invn, vz * invn, 0.f);

  float ns = fsqrt(sx * sx + sy * sy + sz * sz);
#pragma unroll
  for (int off = 32; off; off >>= 1) ns = fmaxf(ns, __shfl_xor(ns, off));
  if ((threadIdx.x & 63) == 0)
    atomicMax((unsigned int*)(ws + OFF_NMAX + b), __float_as_uint(ns));
}

// ---------------------------------------------------------------------------
// Pass 1: row softmax stats over j (exp2 domain). Block = 4 waves on 8 rows,
// j split 4 ways. Loop A: true max d2. Loop B: den sum.
// ---------------------------------------------------------------------------
__global__ __launch_bounds__(256, 4) void k_pass1(float* __restrict__ ws) {
  __shared__ float sred[4][8];
  const float4* u4 = (const float4*)(ws + OFF_U4);
  const float4* w4 = (const float4*)(ws + OFF_W4);
  float2* rowst = (float2*)(ws + OFF_ROW);
  int tid = threadIdx.x, wid = tid >> 6, lane = tid & 63;
  int g0 = blockIdx.x * 8;
  int b = g0 >> 12;

  float ux[8], uy[8], uz[8], us[8];
#pragma unroll
  for (int r = 0; r < 8; r++) {
    float4 u = u4[g0 + r];
    ux[r] = u.x; uy[r] = u.y; uz[r] = u.z; us[r] = u.w;
  }
  const float4* wb = w4 + b * NN;

  float mx[8] = {0.f, 0.f, 0.f, 0.f, 0.f, 0.f, 0.f, 0.f};
  for (int j = wid * 64 + lane; j < NN; j += 256) {
    float4 w = wb[j];
#pragma unroll
    for (int r = 0; r < 8; r++) {
      float dot = ux[r] * w.x + uy[r] * w.y + uz[r] * w.z;
      mx[r] = fmaxf(mx[r], us[r] - dot * dot);
    }
  }
#pragma unroll
  for (int off = 32; off; off >>= 1)
#pragma unroll
    for (int r = 0; r < 8; r++) mx[r] = fmaxf(mx[r], __shfl_xor(mx[r], off));
  if (lane == 0) {
#pragma unroll
    for (int r = 0; r < 8; r++) sred[wid][r] = mx[r];
  }
  __syncthreads();
  float m2[8];
#pragma unroll
  for (int r = 0; r < 8; r++)
    m2[r] = S50 * fsqrt(fmaxf(fmaxf(sred[0][r], sred[1][r]), fmaxf(sred[2][r], sred[3][r])));
  __syncthreads();

  float s[8] = {0.f, 0.f, 0.f, 0.f, 0.f, 0.f, 0.f, 0.f};
  for (int j = wid * 64 + lane; j < NN; j += 256) {
    float4 w = wb[j];
#pragma unroll
    for (int r = 0; r < 8; r++) {
      float dot = ux[r] * w.x + uy[r] * w.y + uz[r] * w.z;
      float d2 = fmaxf(us[r] - dot * dot, 0.f);
      float t = fsqrt(d2);
      s[r] += ex2(fmaf(S50, t, -m2[r]));
    }
  }
#pragma unroll
  for (int off = 32; off; off >>= 1)
#pragma unroll
    for (int r = 0; r < 8; r++) s[r] += __shfl_xor(s[r], off);
  if (lane == 0) {
#pragma unroll
    for (int r = 0; r < 8; r++) sred[wid][r] = s[r];
  }
  __syncthreads();
  if (tid < 8) {
    float tot = sred[0][tid] + sred[1][tid] + sred[2][tid] + sred[3][tid];
    rowst[g0 + tid] = make_float2(m2[tid], 1.f / tot);
  }
}

// ---------------------------------------------------------------------------
// Pass 2: column softmax, row-blocked: block = 8 columns, 4 waves split i,
// lane = i (coalesced float4 loads of u/src/rowst; 8 independent column
// chains per iter). E stored COLUMN-major (coalesced 128B stores). The block
// sweeps all i for its columns, so S_j completes in-block: shuffle + LDS
// reduce, write CS[j] = 1/S directly — no atomics, no zeroing.
// ---------------------------------------------------------------------------
__global__ __launch_bounds__(256, 4) void k_pass2(float* __restrict__ ws) {
  __shared__ float sS[4][8];
  const float4* u4 = (const float4*)(ws + OFF_U4);
  const float4* w4 = (const float4*)(ws + OFF_W4);
  const float4* src4 = (const float4*)(ws + OFF_SRC4);
  const float4* tar4 = (const float4*)(ws + OFF_TAR4);
  const float2* rowst = (const float2*)(ws + OFF_ROW);
  float* CS = ws + OFF_CS;
  _Float16* Eh = (_Float16*)((char*)ws + OFF_EB);

  int tid = threadIdx.x, wid = tid >> 6, lane = tid & 63;
  int c0 = blockIdx.x * 8;        // global column base (b*N + j_local)
  int b = c0 >> 12;
  int base = b * NN;
  float maxns = ws[OFF_NMAX + b];

  float wx[8], wy[8], wz[8], txl[8], tyl[8], tzl[8], Cj[8];
#pragma unroll
  for (int r = 0; r < 8; r++) {
    float4 w = w4[c0 + r];
    float4 tt = tar4[c0 + r];
    wx[r] = w.x; wy[r] = w.y; wz[r] = w.z;
    txl[r] = tt.x * L2E; tyl[r] = tt.y * L2E; tzl[r] = tt.z * L2E;
    Cj[r] = BIAS - maxns * L2E * fsqrt(tt.x * tt.x + tt.y * tt.y + tt.z * tt.z);
  }

  float S[8] = {0.f, 0.f, 0.f, 0.f, 0.f, 0.f, 0.f, 0.f};
  for (int i = wid * 64 + lane; i < NN; i += 256) {
    float4 uv = u4[base + i];
    float4 sv = src4[base + i];
    float2 rs = rowst[base + i];
#pragma unroll
    for (int r = 0; r < 8; r++) {
      float dot = uv.x * wx[r] + uv.y * wy[r] + uv.z * wz[r];
      float d2 = fmaxf(uv.w - dot * dot, 0.f);
      float t = fsqrt(d2);
      float ev = ex2(fmaf(S50, t, -rs.x));
      float wgt = fmaf(-ev, rs.y, 1.f);
      float Ap = sv.x * txl[r] + sv.y * tyl[r] + sv.z * tzl[r];
      float Ev = ex2(fmaf(Ap, wgt, Cj[r]));
      S[r] += Ev;
      Eh[(size_t)(c0 + r) * NN + i] = (_Float16)Ev;
    }
  }
#pragma unroll
  for (int off = 32; off; off >>= 1)
#pragma unroll
    for (int r = 0; r < 8; r++) S[r] += __shfl_xor(S[r], off);
  if (lane == 0) {
#pragma unroll
    for (int r = 0; r < 8; r++) sS[wid][r] = S[r];
  }
  __syncthreads();
  if (tid < 8) {
    float tot = sS[0][tid] + sS[1][tid] + sS[2][tid] + sS[3][tid];
    CS[c0 + tid] = 1.f / tot;
  }
}

// ---------------------------------------------------------------------------
// Pass 3: out[i] += sum_j (E_ij * invS_j) * src_j. Column-major E, lane = i
// (coalesced fp16 loads). Block = 64 rows x 512-j chunk; src/invS staged to
// LDS once (broadcast reads); 4 waves split the chunk; LDS merge + atomicAdd
// into zeroed d_out. Zero transcendentals.
// Grid: 128 i-groups x 8 j-chunks = 1024 blocks.
// ---------------------------------------------------------------------------
__global__ __launch_bounds__(256, 4) void k_pass3(const float* __restrict__ ws,
                                                  float* __restrict__ out) {
  __shared__ float4 ssrc[512];
  __shared__ float sinv[512];
  __shared__ float smrg[4][64][3];
  const float4* src4 = (const float4*)(ws + OFF_SRC4);
  const float* CS = ws + OFF_CS;
  const _Float16* Eh = (const _Float16*)((const char*)ws + OFF_EB);

  int tid = threadIdx.x, wid = tid >> 6, lane = tid & 63;
  int g = blockIdx.x >> 3;        // i-group 0..127
  int c = blockIdx.x & 7;         // j-chunk 0..7
  int b = g >> 6;
  int base = b * NN;
  int i_loc = (g & 63) * 64 + lane;
  int j0 = c * 512;

  ssrc[tid] = src4[base + j0 + tid];
  ssrc[tid + 256] = src4[base + j0 + 256 + tid];
  sinv[tid] = CS[base + j0 + tid];
  sinv[tid + 256] = CS[base + j0 + 256 + tid];
  __syncthreads();

  float a0 = 0.f, a1 = 0.f, a2 = 0.f;
  const _Float16* Ep = Eh + ((size_t)(base + j0 + wid * 128)) * NN + i_loc;
#pragma unroll 4
  for (int jj = 0; jj < 128; ++jj) {
    int jl = wid * 128 + jj;
    float4 sj = ssrc[jl];
    float p = (float)Ep[(size_t)jj * NN] * sinv[jl];
    a0 = fmaf(p, sj.x, a0);
    a1 = fmaf(p, sj.y, a1);
    a2 = fmaf(p, sj.z, a2);
  }
  smrg[wid][lane][0] = a0;
  smrg[wid][lane][1] = a1;
  smrg[wid][lane][2] = a2;
  __syncthreads();
  if (wid == 0) {
    float v0 = smrg[0][lane][0] + smrg[1][lane][0] + smrg[2][lane][0] + smrg[3][lane][0];
    float v1 = smrg[0][lane][1] + smrg[1][lane][1] + smrg[2][lane][1] + smrg[3][lane][1];
    float v2 = smrg[0][lane][2] + smrg[1][lane][2] + smrg[2][lane][2] + smrg[3][lane][2];
    int o = (base + i_loc) * 3;
    atomicAdd(&out[o + 0], v0);
    atomicAdd(&out[o + 1], v1);
    atomicAdd(&out[o + 2], v2);
  }
}

extern "C" void kernel_launch(void* const* d_in, const int* in_sizes, int n_in,
                              void* d_out, int out_size, void* d_ws, size_t ws_size,
                              hipStream_t stream) {
  (void)in_sizes; (void)n_in; (void)ws_size;
  const float* ftar = (const float*)d_in[0];
  const float* fsrc = (const float*)d_in[1];
  const float* K = (const float*)d_in[2];
  const float* R = (const float*)d_in[3];
  const float* t = (const float*)d_in[4];
  float* ws = (float*)d_ws;
  float* out = (float*)d_out;

  // zero per-batch norm-max slots and the output (pass3 accumulates atomically)
  hipMemsetAsync((char*)d_ws + (size_t)OFF_NMAX * sizeof(float), 0, BB * sizeof(float), stream);
  hipMemsetAsync(d_out, 0, (size_t)out_size * sizeof(float), stream);

  k_setup<<<dim3((BB * NN + 255) / 256), dim3(256), 0, stream>>>(fsrc, ftar, K, R, t, ws);
  k_pass1<<<dim3(1024), dim3(256), 0, stream>>>(ws);
  k_pass2<<<dim3(1024), dim3(256), 0, stream>>>(ws);
  k_pass3<<<dim3(1024), dim3(256), 0, stream>>>(ws, out);
}

// Round 9
// 135.016 us; speedup vs baseline: 1.2171x; 1.0424x over previous
//
#include <hip/hip_runtime.h>
#include <hip/hip_bf16.h>

// Problem constants (from reference): B=2, C=3, H=W=64, N=4096.
namespace {
constexpr int BB = 2;
constexpr int NN = 4096;

// Workspace layout. Small fp32 arrays first (element offsets in floats):
constexpr int OFF_SRC4 = 0;             // float4[B*N] (sx,sy,sz,|u|^2)
constexpr int OFF_TAR4 = 4 * BB * NN;   // float4[B*N]
constexpr int OFF_U4   = 8 * BB * NN;   // float4[B*N] (ux,uy,uz,|u|^2)
constexpr int OFF_W4   = 12 * BB * NN;  // float4[B*N] (wx,wy,wz, o.w_j)
constexpr int OFF_ROW  = 16 * BB * NN;  // float2[B*N] (m2_i log2-domain row max, 1/den_i)
constexpr int OFF_CS   = 18 * BB * NN;  // float[B*N]  1/S_j (written whole by pass2)
constexpr int OFF_NMAX = 19 * BB * NN;  // float[B]    max|src| (zeroed)
// fp16 N x N stream, COLUMN-major: E[(global_col)*NN + i_local]
constexpr size_t OFF_EB = (size_t)1 << 20;
constexpr float L2E = 1.4426950408889634f;    // log2(e)
constexpr float S50 = 72.13475204444817f;     // 50 * log2(e)
constexpr float INV_S50 = 0.013862943611198906f;
constexpr float BIAS = 10.0f;                 // fp16 underflow headroom for E
constexpr float SKIP = 30.0f;                 // e < 2^-30 => exactly negligible
}

typedef _Float16 h2 __attribute__((ext_vector_type(2)));

__device__ __forceinline__ float fsqrt(float x) { return __builtin_amdgcn_sqrtf(x); }
__device__ __forceinline__ float ex2(float x) { return __builtin_amdgcn_exp2f(x); }

// ---------------------------------------------------------------------------
// Setup: per-batch M = K R K^-1, o = K t; per-pixel fp32 arrays; max|src| per b.
// ---------------------------------------------------------------------------
__global__ __launch_bounds__(256) void k_setup(
    const float* __restrict__ fsrc, const float* __restrict__ ftar,
    const float* __restrict__ Kb, const float* __restrict__ Rb,
    const float* __restrict__ tb, float* __restrict__ ws) {
  int gid = blockIdx.x * blockDim.x + threadIdx.x;
  if (gid >= BB * NN) return;
  int b = gid >> 12;
  int n = gid & (NN - 1);

  float K[9], R[9], t3[3];
#pragma unroll
  for (int k = 0; k < 9; k++) { K[k] = Kb[b * 9 + k]; R[k] = Rb[b * 9 + k]; }
#pragma unroll
  for (int k = 0; k < 3; k++) t3[k] = tb[b * 3 + k];

  float c00 = K[4] * K[8] - K[5] * K[7];
  float c01 = K[5] * K[6] - K[3] * K[8];
  float c02 = K[3] * K[7] - K[4] * K[6];
  float det = K[0] * c00 + K[1] * c01 + K[2] * c02;
  float id = 1.0f / det;
  float Ki[9];
  Ki[0] = c00 * id; Ki[1] = (K[2] * K[7] - K[1] * K[8]) * id; Ki[2] = (K[1] * K[5] - K[2] * K[4]) * id;
  Ki[3] = c01 * id; Ki[4] = (K[0] * K[8] - K[2] * K[6]) * id; Ki[5] = (K[2] * K[3] - K[0] * K[5]) * id;
  Ki[6] = c02 * id; Ki[7] = (K[1] * K[6] - K[0] * K[7]) * id; Ki[8] = (K[0] * K[4] - K[1] * K[3]) * id;

  float RK[9];
#pragma unroll
  for (int i = 0; i < 3; i++)
#pragma unroll
    for (int j = 0; j < 3; j++)
      RK[i * 3 + j] = R[i * 3 + 0] * Ki[j] + R[i * 3 + 1] * Ki[3 + j] + R[i * 3 + 2] * Ki[6 + j];
  float M3[9];
#pragma unroll
  for (int i = 0; i < 3; i++)
#pragma unroll
    for (int j = 0; j < 3; j++)
      M3[i * 3 + j] = K[i * 3 + 0] * RK[j] + K[i * 3 + 1] * RK[3 + j] + K[i * 3 + 2] * RK[6 + j];
  float o0 = K[0] * t3[0] + K[1] * t3[1] + K[2] * t3[2];
  float o1 = K[3] * t3[0] + K[4] * t3[1] + K[5] * t3[2];
  float o2 = K[6] * t3[0] + K[7] * t3[1] + K[8] * t3[2];

  float sx = fsrc[b * 3 * NN + 0 * NN + n];
  float sy = fsrc[b * 3 * NN + 1 * NN + n];
  float sz = fsrc[b * 3 * NN + 2 * NN + n];
  float tx = ftar[b * 3 * NN + 0 * NN + n];
  float ty = ftar[b * 3 * NN + 1 * NN + n];
  float tz = ftar[b * 3 * NN + 2 * NN + n];

  float ux = sx - o0, uy = sy - o1, uz = sz - o2;
  float usq = ux * ux + uy * uy + uz * uz;

  float px = (float)(n >> 6), py = (float)(n & 63);
  float vx = M3[0] * px + M3[1] * py + M3[2];
  float vy = M3[3] * px + M3[4] * py + M3[5];
  float vz = M3[6] * px + M3[7] * py + M3[8];
  float invn = rsqrtf(vx * vx + vy * vy + vz * vz);
  float wxn = vx * invn, wyn = vy * invn, wzn = vz * invn;
  float ow = o0 * wxn + o1 * wyn + o2 * wzn;

  float4* src4 = (float4*)(ws + OFF_SRC4);
  float4* tar4 = (float4*)(ws + OFF_TAR4);
  float4* u4 = (float4*)(ws + OFF_U4);
  float4* w4 = (float4*)(ws + OFF_W4);
  src4[gid] = make_float4(sx, sy, sz, usq);
  tar4[gid] = make_float4(tx, ty, tz, 0.f);
  u4[gid] = make_float4(ux, uy, uz, usq);
  w4[gid] = make_float4(wxn, wyn, wzn, ow);

  float ns = fsqrt(sx * sx + sy * sy + sz * sz);
#pragma unroll
  for (int off = 32; off; off >>= 1) ns = fmaxf(ns, __shfl_xor(ns, off));
  if ((threadIdx.x & 63) == 0)
    atomicMax((unsigned int*)(ws + OFF_NMAX + b), __float_as_uint(ns));
}

// ---------------------------------------------------------------------------
// Pass 1: row softmax stats over j (exp2 domain). Block = 4 waves on 8 rows,
// j split 4 ways. Loop A: true max d2. Loop B: den sum with wave-coherent
// skip (terms with t < m - 30 log2 are exactly negligible: den >= 1).
// ---------------------------------------------------------------------------
__global__ __launch_bounds__(256, 4) void k_pass1(float* __restrict__ ws) {
  __shared__ float sred[4][8];
  const float4* u4 = (const float4*)(ws + OFF_U4);
  const float4* w4 = (const float4*)(ws + OFF_W4);
  float2* rowst = (float2*)(ws + OFF_ROW);
  int tid = threadIdx.x, wid = tid >> 6, lane = tid & 63;
  int g0 = blockIdx.x * 8;
  int b = g0 >> 12;

  float ux[8], uy[8], uz[8], us[8];
#pragma unroll
  for (int r = 0; r < 8; r++) {
    float4 u = u4[g0 + r];
    ux[r] = u.x; uy[r] = u.y; uz[r] = u.z; us[r] = u.w;
  }
  const float4* wb = w4 + b * NN;

  // Loop A: exact max d2
  float mx[8] = {0.f, 0.f, 0.f, 0.f, 0.f, 0.f, 0.f, 0.f};
  for (int j = wid * 64 + lane; j < NN; j += 256) {
    float4 w = wb[j];
#pragma unroll
    for (int r = 0; r < 8; r++) {
      float dot = ux[r] * w.x + uy[r] * w.y + uz[r] * w.z;
      mx[r] = fmaxf(mx[r], us[r] - dot * dot);
    }
  }
#pragma unroll
  for (int off = 32; off; off >>= 1)
#pragma unroll
    for (int r = 0; r < 8; r++) mx[r] = fmaxf(mx[r], __shfl_xor(mx[r], off));
  if (lane == 0) {
#pragma unroll
    for (int r = 0; r < 8; r++) sred[wid][r] = mx[r];
  }
  __syncthreads();
  float m2[8], thr2[8];
#pragma unroll
  for (int r = 0; r < 8; r++) {
    m2[r] = S50 * fsqrt(fmaxf(fmaxf(sred[0][r], sred[1][r]), fmaxf(sred[2][r], sred[3][r])));
    float thr = (m2[r] - SKIP) * INV_S50;
    thr2[r] = (m2[r] > SKIP) ? thr * thr : -1.0f;  // -1: never skip
  }
  __syncthreads();

  // Loop B: den sum, skipping wave-coherent all-cold j's
  float s[8] = {0.f, 0.f, 0.f, 0.f, 0.f, 0.f, 0.f, 0.f};
  for (int j = wid * 64 + lane; j < NN; j += 256) {
    float4 w = wb[j];
    float d2v[8];
    int full = 0;
#pragma unroll
    for (int r = 0; r < 8; r++) {
      float dot = ux[r] * w.x + uy[r] * w.y + uz[r] * w.z;
      d2v[r] = fmaf(-dot, dot, us[r]);
      full |= (d2v[r] >= thr2[r]) ? 1 : 0;
    }
    if (__any(full)) {
#pragma unroll
      for (int r = 0; r < 8; r++) {
        float t = fsqrt(fmaxf(d2v[r], 0.f));
        s[r] += ex2(fmaf(S50, t, -m2[r]));
      }
    }
  }
#pragma unroll
  for (int off = 32; off; off >>= 1)
#pragma unroll
    for (int r = 0; r < 8; r++) s[r] += __shfl_xor(s[r], off);
  if (lane == 0) {
#pragma unroll
    for (int r = 0; r < 8; r++) sred[wid][r] = s[r];
  }
  __syncthreads();
  if (tid < 8) {
    float tot = sred[0][tid] + sred[1][tid] + sred[2][tid] + sred[3][tid];
    rowst[g0 + tid] = make_float2(m2[tid], 1.f / tot);
  }
}

// ---------------------------------------------------------------------------
// Pass 2: column softmax. Block = 8 columns, 4 waves split i, lane = i.
// dot(u,w) = src.w_j - (o.w_j) (no u4 load; ow folded in w4.w, usq in src4.w).
// e-path (sqrt + exp2 + fma) skipped when all 64 lanes have t < m-30:
// then wgt == 1 exactly in fp32. E stored column-major, nontemporal.
// S_j completes in-block: no atomics.
// ---------------------------------------------------------------------------
__global__ __launch_bounds__(256, 4) void k_pass2(float* __restrict__ ws) {
  __shared__ float sS[4][8];
  const float4* w4 = (const float4*)(ws + OFF_W4);
  const float4* src4 = (const float4*)(ws + OFF_SRC4);
  const float4* tar4 = (const float4*)(ws + OFF_TAR4);
  const float2* rowst = (const float2*)(ws + OFF_ROW);
  float* CS = ws + OFF_CS;
  _Float16* Eh = (_Float16*)((char*)ws + OFF_EB);

  int tid = threadIdx.x, wid = tid >> 6, lane = tid & 63;
  int c0 = blockIdx.x * 8;        // global column base (b*N + j_local)
  int b = c0 >> 12;
  int base = b * NN;
  float maxns = ws[OFF_NMAX + b];

  float wx[8], wy[8], wz[8], now[8], txl[8], tyl[8], tzl[8], Cj[8];
#pragma unroll
  for (int r = 0; r < 8; r++) {
    float4 w = w4[c0 + r];
    float4 tt = tar4[c0 + r];
    wx[r] = w.x; wy[r] = w.y; wz[r] = w.z; now[r] = -w.w;
    txl[r] = tt.x * L2E; tyl[r] = tt.y * L2E; tzl[r] = tt.z * L2E;
    Cj[r] = BIAS - maxns * L2E * fsqrt(tt.x * tt.x + tt.y * tt.y + tt.z * tt.z);
  }

  float S[8] = {0.f, 0.f, 0.f, 0.f, 0.f, 0.f, 0.f, 0.f};
  for (int i = wid * 64 + lane; i < NN; i += 256) {
    float4 sv = src4[base + i];          // .w = |u_i|^2
    float2 rs = rowst[base + i];         // (m2_i, invden_i)
    float thr = (rs.x - SKIP) * INV_S50;
    float thr2 = (rs.x > SKIP) ? thr * thr : -1.0f;
#pragma unroll
    for (int r = 0; r < 8; r++) {
      float dot = fmaf(sv.x, wx[r], fmaf(sv.y, wy[r], fmaf(sv.z, wz[r], now[r])));
      float d2 = fmaf(-dot, dot, sv.w);
      float Ap = fmaf(sv.x, txl[r], fmaf(sv.y, tyl[r], sv.z * tzl[r]));
      float wgt = 1.0f;
      if (__any(d2 >= thr2)) {
        float t = fsqrt(fmaxf(d2, 0.f));
        float ev = ex2(fmaf(S50, t, -rs.x));
        wgt = fmaf(-ev, rs.y, 1.f);
      }
      float Ev = ex2(fmaf(Ap, wgt, Cj[r]));
      S[r] += Ev;
      __builtin_nontemporal_store((_Float16)Ev, &Eh[(size_t)(c0 + r) * NN + i]);
    }
  }
#pragma unroll
  for (int off = 32; off; off >>= 1)
#pragma unroll
    for (int r = 0; r < 8; r++) S[r] += __shfl_xor(S[r], off);
  if (lane == 0) {
#pragma unroll
    for (int r = 0; r < 8; r++) sS[wid][r] = S[r];
  }
  __syncthreads();
  if (tid < 8) {
    float tot = sS[0][tid] + sS[1][tid] + sS[2][tid] + sS[3][tid];
    CS[c0 + tid] = 1.f / tot;
  }
}

// ---------------------------------------------------------------------------
// Pass 3: out[i] += sum_j (E_ij * invS_j) * src_j. Column-major E, each lane
// owns 2 adjacent rows (packed 2xfp16 loads). Block = 128 rows x 256-j chunk;
// src/invS staged to LDS; 4 waves split the chunk; LDS merge + atomicAdd.
// Grid: 64 i-groups x 16 j-chunks = 1024 blocks. Zero transcendentals.
// ---------------------------------------------------------------------------
__global__ __launch_bounds__(256, 4) void k_pass3(const float* __restrict__ ws,
                                                  float* __restrict__ out) {
  __shared__ float4 ssrc[256];
  __shared__ float sinv[256];
  __shared__ float smrg[4][128][3];
  const float4* src4 = (const float4*)(ws + OFF_SRC4);
  const float* CS = ws + OFF_CS;
  const _Float16* Eh = (const _Float16*)((const char*)ws + OFF_EB);

  int tid = threadIdx.x, wid = tid >> 6, lane = tid & 63;
  int g = blockIdx.x >> 4;        // i-group 0..63 (128 rows each)
  int c = blockIdx.x & 15;        // j-chunk 0..15 (256 cols each)
  int b = g >> 5;
  int base = b * NN;
  int i0 = (g & 31) * 128 + lane * 2;
  int j0 = c * 256;

  ssrc[tid] = src4[base + j0 + tid];
  sinv[tid] = CS[base + j0 + tid];
  __syncthreads();

  float a00 = 0.f, a01 = 0.f, a02 = 0.f, a10 = 0.f, a11 = 0.f, a12 = 0.f;
#pragma unroll 4
  for (int jj = 0; jj < 64; ++jj) {
    int jl = wid * 64 + jj;
    float4 sj = ssrc[jl];
    float iv = sinv[jl];
    h2 e2 = *(const h2*)&Eh[(size_t)(base + j0 + jl) * NN + i0];
    float p0 = (float)e2.x * iv;
    float p1 = (float)e2.y * iv;
    a00 = fmaf(p0, sj.x, a00); a01 = fmaf(p0, sj.y, a01); a02 = fmaf(p0, sj.z, a02);
    a10 = fmaf(p1, sj.x, a10); a11 = fmaf(p1, sj.y, a11); a12 = fmaf(p1, sj.z, a12);
  }
  smrg[wid][lane * 2 + 0][0] = a00;
  smrg[wid][lane * 2 + 0][1] = a01;
  smrg[wid][lane * 2 + 0][2] = a02;
  smrg[wid][lane * 2 + 1][0] = a10;
  smrg[wid][lane * 2 + 1][1] = a11;
  smrg[wid][lane * 2 + 1][2] = a12;
  __syncthreads();
  if (tid < 128) {
    int gi = base + (g & 31) * 128 + tid;
#pragma unroll
    for (int cc = 0; cc < 3; cc++) {
      float v = smrg[0][tid][cc] + smrg[1][tid][cc] + smrg[2][tid][cc] + smrg[3][tid][cc];
      atomicAdd(&out[gi * 3 + cc], v);
    }
  }
}

extern "C" void kernel_launch(void* const* d_in, const int* in_sizes, int n_in,
                              void* d_out, int out_size, void* d_ws, size_t ws_size,
                              hipStream_t stream) {
  (void)in_sizes; (void)n_in; (void)ws_size;
  const float* ftar = (const float*)d_in[0];
  const float* fsrc = (const float*)d_in[1];
  const float* K = (const float*)d_in[2];
  const float* R = (const float*)d_in[3];
  const float* t = (const float*)d_in[4];
  float* ws = (float*)d_ws;
  float* out = (float*)d_out;

  // zero per-batch norm-max slots and the output (pass3 accumulates atomically)
  hipMemsetAsync((char*)d_ws + (size_t)OFF_NMAX * sizeof(float), 0, BB * sizeof(float), stream);
  hipMemsetAsync(d_out, 0, (size_t)out_size * sizeof(float), stream);

  k_setup<<<dim3((BB * NN + 255) / 256), dim3(256), 0, stream>>>(fsrc, ftar, K, R, t, ws);
  k_pass1<<<dim3(1024), dim3(256), 0, stream>>>(ws);
  k_pass2<<<dim3(1024), dim3(256), 0, stream>>>(ws);
  k_pass3<<<dim3(1024), dim3(256), 0, stream>>>(ws, out);
}